// Round 18
// baseline (374.393 us; speedup 1.0000x reference)
//
#include <hip/hip_runtime.h>
#include <hip/hip_bf16.h>
#include <math.h>

#define Bn 4
#define Sn 1024
#define Dn 2048
#define Hn 16
#define DHn 128
#define BS (Bn * Sn)       // 4096
#define QKVC (3 * Dn)      // 6144

typedef __attribute__((ext_vector_type(8))) short short8;   // 8 x bf16
typedef __attribute__((ext_vector_type(4))) float float4v;  // MFMA acc

// f32 -> bf16 (round-to-nearest-even)
__device__ inline unsigned short f2bf(float x) {
  union { float f; unsigned int u; } v; v.f = x;
  unsigned int r = v.u + 0x7fffu + ((v.u >> 16) & 1u);
  return (unsigned short)(r >> 16);
}
__device__ inline float bf2f(unsigned short b) {
  union { unsigned int u; float f; } v; v.u = ((unsigned int)b) << 16;
  return v.f;
}

// async global->LDS, 16B per lane. LDS dest = wave-uniform base + lane*16.
__device__ __forceinline__ void gload16(const unsigned short* g, unsigned short* l) {
  __builtin_amdgcn_global_load_lds(
      (const __attribute__((address_space(1))) unsigned int*)g,
      (__attribute__((address_space(3))) unsigned int*)l, 16, 0, 0);
}

// ---------------------------------------------------------------------------
// Merged prep: x cvt (blocks 0..4095), w_qkv transpose+cvt (4096..7167),
// w_out transpose+cvt (7168..8191).
// ---------------------------------------------------------------------------
__device__ void tc_body(const float* __restrict__ w, unsigned short* __restrict__ wT,
                        int K, int N, int bx, int by, int tid,
                        unsigned short (*t)[72]) {
  const int c0 = bx * 64;  // N
  const int r0 = by * 64;  // K
  const int r = tid >> 2;
  const int cb = (tid & 3) * 16;
#pragma unroll
  for (int it = 0; it < 4; ++it) {
    float4 v = *reinterpret_cast<const float4*>(&w[(long)(r0 + r) * N + c0 + cb + 4 * it]);
    t[r][cb + 4 * it + 0] = f2bf(v.x);
    t[r][cb + 4 * it + 1] = f2bf(v.y);
    t[r][cb + 4 * it + 2] = f2bf(v.z);
    t[r][cb + 4 * it + 3] = f2bf(v.w);
  }
  __syncthreads();
  unsigned short o[16];
#pragma unroll
  for (int e = 0; e < 16; ++e) o[e] = t[cb + e][r];
  unsigned short* dst = &wT[(long)(c0 + r) * K + r0 + cb];
  *reinterpret_cast<short8*>(dst) = *reinterpret_cast<short8*>(&o[0]);
  *reinterpret_cast<short8*>(dst + 8) = *reinterpret_cast<short8*>(&o[8]);
}

__global__ __launch_bounds__(256) void prep_all(
    const float* __restrict__ x, const float* __restrict__ w_qkv,
    const float* __restrict__ w_out, unsigned short* __restrict__ x16,
    unsigned short* __restrict__ wqkvT, unsigned short* __restrict__ woutT) {
  __shared__ unsigned short t[64][72];
  const int bid = blockIdx.x;
  const int tid = threadIdx.x;
  if (bid < 4096) {
    const int id = bid * 256 + tid;
    const float4* p = reinterpret_cast<const float4*>(x) + 2 * (size_t)id;
    float4 a = p[0], b = p[1];
    short8 o;
    o[0] = (short)f2bf(a.x); o[1] = (short)f2bf(a.y);
    o[2] = (short)f2bf(a.z); o[3] = (short)f2bf(a.w);
    o[4] = (short)f2bf(b.x); o[5] = (short)f2bf(b.y);
    o[6] = (short)f2bf(b.z); o[7] = (short)f2bf(b.w);
    *reinterpret_cast<short8*>(x16 + 8 * (size_t)id) = o;
  } else if (bid < 7168) {
    const int lb = bid - 4096;
    tc_body(w_qkv, wqkvT, Dn, QKVC, lb % 96, lb / 96, tid, t);
  } else {
    const int lb = bid - 7168;
    tc_body(w_out, woutT, Dn, Dn, lb % 32, lb / 32, tid, t);
  }
}

// ---------------------------------------------------------------------------
// 128x128-tile GEMM, BK=64, 256 thr = 4 waves (2M x 2N), 64x64/wave.
// A: LDS dbuf 2x16KB (gload_lds, XOR-window swizzle). B: DIRECT global->reg
// fragments, double-buffered one K-tile ahead (b0/b1) — no LDS for B at all.
// Halves LDS traffic (the measured bottleneck at R17); B panel is L2-hot
// under the group-of-8 n-ordering. Loads drain at the per-tile barrier.
// ---------------------------------------------------------------------------
#define ABUF(buf) ((buf) * 8192)              // shorts, A dbuf only (32 KB)

#define TILE_MAP()                                                             \
  const int nwg = gridDim.x * gridDim.y;                                       \
  const int bid = blockIdx.y * gridDim.x + blockIdx.x;                         \
  const int swz = (bid & 7) * (nwg >> 3) + (bid >> 3);                         \
  const int t_ = swz & 255, grp_ = swz >> 8;                                   \
  const int m0 = (t_ >> 3) * 128;                                              \
  const int n0 = ((t_ & 7) + grp_ * 8) * 128;

#define LOADB(BT_, K_, k0_, bf_)                                               \
  _Pragma("unroll") for (int ni = 0; ni < 4; ++ni)                             \
    _Pragma("unroll") for (int ks = 0; ks < 2; ++ks)                           \
      bf_[ni][ks] = *(const short8*)((BT_) +                                   \
          (long)(n0 + wc * 64 + ni * 16 + c) * (K_) + (k0_) + (ks * 4 + g) * 8);

#define GEMM_BODY(BUF, BREG)                                                   \
  {                                                                            \
    short8 afr[4][2];                                                          \
    _Pragma("unroll") for (int mi = 0; mi < 4; ++mi)                           \
      _Pragma("unroll") for (int ks = 0; ks < 2; ++ks)                         \
        afr[mi][ks] = *(const short8*)(lds + ABUF(BUF) +                       \
            (wr * 64 + mi * 16 + c) * 64 + (((ks * 4 + g) ^ cg7) << 3));       \
    __builtin_amdgcn_s_setprio(1);                                             \
    _Pragma("unroll") for (int mi = 0; mi < 4; ++mi)                           \
      _Pragma("unroll") for (int ni = 0; ni < 4; ++ni)                         \
        _Pragma("unroll") for (int ks = 0; ks < 2; ++ks)                       \
          acc[mi][ni] = __builtin_amdgcn_mfma_f32_16x16x32_bf16(               \
              afr[mi][ks], BREG[ni][ks], acc[mi][ni], 0, 0, 0);                \
    __builtin_amdgcn_s_setprio(0);                                             \
    __syncthreads();                                                           \
  }

#define GEMM128_LOOP(A_, BT_, K_)                                              \
  short8 b0[4][2], b1[4][2];                                                   \
  STAGE(A_ + (long)m0 * K_, ABUF(0));                                          \
  LOADB(BT_, K_, 0, b0)                                                        \
  __syncthreads();                                                             \
  for (int t2 = 0; t2 < nt / 2; ++t2) {                                        \
    const int t = 2 * t2;                                                      \
    STAGE(A_ + (long)m0 * K_ + (long)(t + 1) * 64, ABUF(1));                   \
    LOADB(BT_, K_, (long)(t + 1) * 64, b1)                                     \
    GEMM_BODY(0, b0)                                                           \
    if (t + 2 < nt) {                                                          \
      STAGE(A_ + (long)m0 * K_ + (long)(t + 2) * 64, ABUF(0));                 \
      LOADB(BT_, K_, (long)(t + 2) * 64, b0)                                   \
    }                                                                          \
    GEMM_BODY(1, b1)                                                           \
  }

// ---------------------------------------------------------------------------
// QKV GEMM with fused rope + head-split + V-transpose epilogue.
// Epilogue in two halves ([128][72] = 18.4 KB fits the 32 KB pool) — the
// R16-verified form.
// ---------------------------------------------------------------------------
__global__ __launch_bounds__(256, 2) void gemm_qkv(
    const unsigned short* __restrict__ A, const unsigned short* __restrict__ BT,
    const float* __restrict__ rope, const int* __restrict__ tpos,
    unsigned short* __restrict__ qR, unsigned short* __restrict__ kR,
    unsigned short* __restrict__ vT, int K) {
  __shared__ unsigned short lds[16384];  // 32 KiB (A dbuf)
  const int tid = threadIdx.x;
  const int wid = tid >> 6, lane = tid & 63;
  const int c = lane & 15, g = lane >> 4;
  const int wr = wid >> 1, wc = wid & 1;
  const int cg7 = c & 7;

  TILE_MAP()

  const int nt = K >> 6;

  float4v acc[4][4];
#pragma unroll
  for (int i = 0; i < 4; ++i)
#pragma unroll
    for (int j = 0; j < 4; ++j) acc[i][j] = (float4v){0.f, 0.f, 0.f, 0.f};

  auto STAGE = [&](const unsigned short* gbase, int sbase) {
#pragma unroll
    for (int j = 0; j < 4; ++j) {
      const int ch = j * 256 + tid;     // 0..1023
      const int r = ch >> 3;            // 0..127
      const int wo = (ch & 7) ^ (r & 7);
      gload16(gbase + (long)r * K + wo * 8, lds + sbase + j * 2048 + wid * 512);
    }
  };

  GEMM128_LOOP(A, BT, K)

  // ---- fused epilogue (two halves; nothing in flight after final barrier) --
  const int type = n0 >> 11;            // 0=q 1=k 2=v
  const int h = (n0 & 2047) >> 7;
  const long bh = (long)((m0 >> 10) * Hn + h);
  const int s0 = m0 & 1023;

  if (type == 2) {
    // V: transposed store in two s-halves (split by wr).
#pragma unroll
    for (int half = 0; half < 2; ++half) {
      if (wr == half) {
#pragma unroll
        for (int mi = 0; mi < 4; ++mi)
#pragma unroll
          for (int ni = 0; ni < 4; ++ni)
#pragma unroll
            for (int j = 0; j < 4; ++j) {
              const int mml = mi * 16 + g * 4 + j;        // local s 0..63
              const int nn = wc * 64 + ni * 16 + c;       // d 0..127
              lds[nn * 72 + mml] = f2bf(acc[mi][ni][j]);
            }
      }
      __syncthreads();
      unsigned short* dst = vT + bh * (long)DHn * Sn + s0 + half * 64;
#pragma unroll
      for (int it = 0; it < 4; ++it) {
        const int cid = it * 256 + tid;
        const int d = cid >> 3;            // 0..127
        const int sl = (cid & 7) * 8;      // 0..56
        short8 v = *reinterpret_cast<const short8*>(lds + d * 72 + sl);
        *reinterpret_cast<short8*>(dst + (long)d * Sn + sl) = v;
      }
      __syncthreads();
    }
  } else {
    // q/k: rope via LDS in two column-halves (split by wc).
    unsigned short* base = (type == 0 ? qR : kR) + (bh * Sn + s0) * DHn;
    const float qsc = (type == 0) ? 0.1275174213f : 1.0f;  // log2(e)/sqrt(128)
#pragma unroll
    for (int half = 0; half < 2; ++half) {
      if (wc == half) {
#pragma unroll
        for (int mi = 0; mi < 4; ++mi)
#pragma unroll
          for (int ni = 0; ni < 4; ++ni)
#pragma unroll
            for (int j = 0; j < 4; ++j) {
              const int mm = wr * 64 + mi * 16 + g * 4 + j;  // s 0..127
              const int nnl = ni * 16 + c;                   // local d 0..63
              lds[mm * 72 + nnl] = f2bf(acc[mi][ni][j]);
            }
      }
      __syncthreads();
#pragma unroll
      for (int it = 0; it < 4; ++it) {
        const int cid = it * 256 + tid;
        const int r = cid >> 3;            // 0..127 (s-local)
        const int colc = (cid & 7) * 8;    // 0..56 local d
        const int gcol = half * 64 + colc; // global d
        union { short8 v; unsigned short u[8]; } iw, ow;
        iw.v = *reinterpret_cast<const short8*>(lds + r * 72 + colc);
        const int pos = tpos[s0 + r];
        const float4* pe = reinterpret_cast<const float4*>(rope) +
                           (long)pos * 64 + (gcol >> 1);
#pragma unroll
        for (int p = 0; p < 4; ++p) {
          const float4 m2 = pe[p];
          const float xx = bf2f(iw.u[2 * p]), yy = bf2f(iw.u[2 * p + 1]);
          ow.u[2 * p]     = f2bf((m2.x * xx + m2.y * yy) * qsc);
          ow.u[2 * p + 1] = f2bf((m2.z * xx + m2.w * yy) * qsc);
        }
        *reinterpret_cast<short8*>(base + (long)r * DHn + gcol) = ow.v;
      }
      __syncthreads();
    }
  }
}

// ---------------------------------------------------------------------------
// Out-proj GEMM (f32 out), same reg-B main loop, direct f32 epilogue.
// ---------------------------------------------------------------------------
__global__ __launch_bounds__(256, 2) void gemm_out(
    const unsigned short* __restrict__ A, const unsigned short* __restrict__ BT,
    float* __restrict__ Cout, int N, int K) {
  __shared__ unsigned short lds[16384];
  const int tid = threadIdx.x;
  const int wid = tid >> 6, lane = tid & 63;
  const int c = lane & 15, g = lane >> 4;
  const int wr = wid >> 1, wc = wid & 1;
  const int cg7 = c & 7;

  TILE_MAP()

  const int nt = K >> 6;

  float4v acc[4][4];
#pragma unroll
  for (int i = 0; i < 4; ++i)
#pragma unroll
    for (int j = 0; j < 4; ++j) acc[i][j] = (float4v){0.f, 0.f, 0.f, 0.f};

  auto STAGE = [&](const unsigned short* gbase, int sbase) {
#pragma unroll
    for (int j = 0; j < 4; ++j) {
      const int ch = j * 256 + tid;
      const int r = ch >> 3;
      const int wo = (ch & 7) ^ (r & 7);
      gload16(gbase + (long)r * K + wo * 8, lds + sbase + j * 2048 + wid * 512);
    }
  };

  GEMM128_LOOP(A, BT, K)

#pragma unroll
  for (int mi = 0; mi < 4; ++mi)
#pragma unroll
    for (int ni = 0; ni < 4; ++ni)
#pragma unroll
      for (int j = 0; j < 4; ++j) {
        const int m = m0 + wr * 64 + mi * 16 + g * 4 + j;
        const int n = n0 + wc * 64 + ni * 16 + c;
        Cout[(long)m * N + n] = acc[mi][ni][j];
      }
}
#undef GEMM128_LOOP
#undef GEMM_BODY
#undef LOADB
#undef TILE_MAP

// ---------------------------------------------------------------------------
// Flash attention v4 (R14-verified, unchanged): 4 waves, KVBLK=64 dbuf,
// QBLK=128 via two q-subtiles; CU-balanced heavy+light pairing.
// ---------------------------------------------------------------------------
__global__ __launch_bounds__(256, 2) void attn_mfma(
    const unsigned short* __restrict__ qR, const unsigned short* __restrict__ kR,
    const unsigned short* __restrict__ vTd, unsigned short* __restrict__ ctx) {
  __shared__ unsigned short lds[32768];   // K dbuf @0/8192, V dbuf @16384/24576
  __shared__ unsigned short Ps[4][16][72];
  const int n = blockIdx.x;
  const int qp = (n < 256) ? (7 - (n >> 6)) : ((n - 256) >> 6);
  const int hb = n & 63;
  const int h = hb >> 2, b = hb & 3;
  const int tid = threadIdx.x, wid = tid >> 6, lane = tid & 63;
  const int c = lane & 15, g = lane >> 4, cg7 = c & 7;
  const long bh = (long)(b * Hn + h);
  const unsigned short* kbase = kR + bh * Sn * DHn;
  const unsigned short* vbase = vTd + bh * DHn * Sn;

  short8 qf[2][4];
#pragma unroll
  for (int sub = 0; sub < 2; ++sub) {
    const unsigned short* qrow =
        qR + (bh * Sn + qp * 128 + sub * 64 + wid * 16 + c) * DHn;
#pragma unroll
    for (int kc = 0; kc < 4; ++kc)
      qf[sub][kc] = *reinterpret_cast<const short8*>(qrow + kc * 32 + g * 8);
  }

  auto STAGE = [&](int kt, int buf) {
#pragma unroll
    for (int j = 0; j < 4; ++j) {  // K tile [64][128]
      const int ch = j * 256 + tid;
      const int r = ch >> 4, wd = ch & 15;
      const int ws = (wd & 8) | ((wd & 7) ^ (r & 7));
      gload16(kbase + (long)kt * 8192 + r * 128 + ws * 8,
              lds + buf * 8192 + j * 2048 + wid * 512);
    }
#pragma unroll
    for (int j = 0; j < 4; ++j) {  // V^T tile [128][64]
      const int ch = j * 256 + tid;
      const int d = ch >> 3, sw = ch & 7;
      gload16(vbase + (long)d * Sn + kt * 64 + ((sw ^ (d & 7)) << 3),
              lds + 16384 + buf * 8192 + j * 2048 + wid * 512);
    }
  };

  float m[2] = {-INFINITY, -INFINITY}, lsum[2] = {0.f, 0.f};
  float4v otA[8], otB[8];
#pragma unroll
  for (int fd = 0; fd < 8; ++fd) {
    otA[fd] = (float4v){0.f, 0.f, 0.f, 0.f};
    otB[fd] = (float4v){0.f, 0.f, 0.f, 0.f};
  }

  const int ntt = 2 * qp + 2;
  STAGE(0, 0);
  __syncthreads();
  int cur = 0;

  for (int kt = 0; kt < ntt; ++kt) {
    if (kt + 1 < ntt) STAGE(kt + 1, cur ^ 1);

#pragma unroll
    for (int sub = 0; sub < 2; ++sub) {
      if (sub == 0 && kt == ntt - 1) continue;
      float4v* ot = (sub == 0) ? otA : otB;

      float4v scv[4];
#pragma unroll
      for (int f = 0; f < 4; ++f) scv[f] = (float4v){0.f, 0.f, 0.f, 0.f};
      __builtin_amdgcn_s_setprio(1);
#pragma unroll
      for (int f = 0; f < 4; ++f)
#pragma unroll
        for (int kc = 0; kc < 4; ++kc) {
          const int wp = kc * 4 + g;
          const int ws = (wp & 8) | ((wp & 7) ^ cg7);
          short8 kf = *reinterpret_cast<const short8*>(
              lds + cur * 8192 + (f * 16 + c) * 128 + ws * 8);
          scv[f] = __builtin_amdgcn_mfma_f32_16x16x32_bf16(kf, qf[sub][kc],
                                                           scv[f], 0, 0, 0);
        }
      __builtin_amdgcn_s_setprio(0);

      if (kt == 2 * qp + sub) {
        const int qloc = wid * 16 + c;
#pragma unroll
        for (int f = 0; f < 4; ++f)
#pragma unroll
          for (int j = 0; j < 4; ++j)
            if (f * 16 + g * 4 + j > qloc) scv[f][j] = -INFINITY;
      }

      float tmax = -INFINITY;
#pragma unroll
      for (int f = 0; f < 4; ++f)
#pragma unroll
        for (int j = 0; j < 4; ++j) tmax = fmaxf(tmax, scv[f][j]);
      tmax = fmaxf(tmax, __shfl_xor(tmax, 16));
      tmax = fmaxf(tmax, __shfl_xor(tmax, 32));

      float mnew, corr;
      if (__all(tmax <= m[sub] + 8.f)) {  // defer-max
        mnew = m[sub]; corr = 1.f;
      } else {
        mnew = fmaxf(m[sub], tmax);
        corr = exp2f(m[sub] - mnew);
#pragma unroll
        for (int fd = 0; fd < 8; ++fd) ot[fd] *= corr;
      }
      float psum = 0.f;
#pragma unroll
      for (int f = 0; f < 4; ++f)
#pragma unroll
        for (int j = 0; j < 4; ++j) {
          scv[f][j] = exp2f(scv[f][j] - mnew);
          psum += scv[f][j];
        }
      psum += __shfl_xor(psum, 16);
      psum += __shfl_xor(psum, 32);
      lsum[sub] = lsum[sub] * corr + psum;
      m[sub] = mnew;

#pragma unroll
      for (int f = 0; f < 4; ++f) {
        unsigned int lo = (unsigned)f2bf(scv[f][0]) | ((unsigned)f2bf(scv[f][1]) << 16);
        unsigned int hi = (unsigned)f2bf(scv[f][2]) | ((unsigned)f2bf(scv[f][3]) << 16);
        uint2 pk; pk.x = lo; pk.y = hi;
        *reinterpret_cast<uint2*>(&Ps[wid][c][f * 16 + g * 4]) = pk;
      }

      short8 pf0 = *reinterpret_cast<const short8*>(&Ps[wid][c][g * 8]);
      short8 pf1 = *reinterpret_cast<const short8*>(&Ps[wid][c][32 + g * 8]);
      __builtin_amdgcn_s_setprio(1);
#pragma unroll
      for (int fd = 0; fd < 8; ++fd) {
        short8 vf0 = *reinterpret_cast<const short8*>(
            lds + 16384 + cur * 8192 + (fd * 16 + c) * 64 + ((g ^ cg7) << 3));
        short8 vf1 = *reinterpret_cast<const short8*>(
            lds + 16384 + cur * 8192 + (fd * 16 + c) * 64 + (((g + 4) ^ cg7) << 3));
        ot[fd] = __builtin_amdgcn_mfma_f32_16x16x32_bf16(vf0, pf0, ot[fd], 0, 0, 0);
        ot[fd] = __builtin_amdgcn_mfma_f32_16x16x32_bf16(vf1, pf1, ot[fd], 0, 0, 0);
      }
      __builtin_amdgcn_s_setprio(0);
    }

    __syncthreads();
    cur ^= 1;
  }

#pragma unroll
  for (int sub = 0; sub < 2; ++sub) {
    const float4v* ot = (sub == 0) ? otA : otB;
    const float inv = 1.0f / lsum[sub];
    unsigned short* orow =
        ctx + (long)(b * Sn + qp * 128 + sub * 64 + wid * 16 + c) * Dn + h * DHn;
#pragma unroll
    for (int fd = 0; fd < 8; ++fd) {
      const int d = fd * 16 + g * 4;
      uint2 pk;
      pk.x = (unsigned)f2bf(ot[fd][0] * inv) | ((unsigned)f2bf(ot[fd][1] * inv) << 16);
      pk.y = (unsigned)f2bf(ot[fd][2] * inv) | ((unsigned)f2bf(ot[fd][3] * inv) << 16);
      *reinterpret_cast<uint2*>(orow + d) = pk;
    }
  }
}

// ---------------------------------------------------------------------------
extern "C" void kernel_launch(void* const* d_in, const int* in_sizes, int n_in,
                              void* d_out, int out_size, void* d_ws, size_t ws_size,
                              hipStream_t stream) {
  const float* x     = (const float*)d_in[0];
  const float* w_qkv = (const float*)d_in[1];
  const float* w_out = (const float*)d_in[2];
  const float* rope  = (const float*)d_in[3];
  const int*   tpos  = (const int*)d_in[4];
  float* out = (float*)d_out;

  unsigned short* x16    = (unsigned short*)d_ws;
  unsigned short* wqkvT  = x16 + (size_t)BS * Dn;
  unsigned short* woutT  = wqkvT + (size_t)Dn * QKVC;
  unsigned short* qR     = woutT + (size_t)Dn * Dn;
  unsigned short* kR     = qR + (size_t)BS * Dn;
  unsigned short* vT16   = kR + (size_t)BS * Dn;
  unsigned short* ctx16  = vT16 + (size_t)BS * Dn;

  prep_all<<<8192, 256, 0, stream>>>(x, w_qkv, w_out, x16, wqkvT, woutT);
  {
    dim3 grid(BS / 128, QKVC / 128);  // 32 x 48 = 1536
    gemm_qkv<<<grid, 256, 0, stream>>>(x16, wqkvT, rope, tpos, qR, kR, vT16, Dn);
  }
  attn_mfma<<<512, 256, 0, stream>>>(qR, kR, vT16, ctx16);
  {
    dim3 grid(BS / 128, Dn / 128);    // 32 x 16 = 512
    gemm_out<<<grid, 256, 0, stream>>>(ctx16, woutT, out, Dn, Dn);
  }
}

// Round 19
// 209.690 us; speedup vs baseline: 1.7855x; 1.7855x over previous
//
#include <hip/hip_runtime.h>
#include <hip/hip_bf16.h>
#include <math.h>

#define Bn 4
#define Sn 1024
#define Dn 2048
#define Hn 16
#define DHn 128
#define BS (Bn * Sn)       // 4096
#define QKVC (3 * Dn)      // 6144

typedef __attribute__((ext_vector_type(8))) short short8;   // 8 x bf16
typedef __attribute__((ext_vector_type(4))) float float4v;  // MFMA acc

// f32 -> bf16 (round-to-nearest-even)
__device__ inline unsigned short f2bf(float x) {
  union { float f; unsigned int u; } v; v.f = x;
  unsigned int r = v.u + 0x7fffu + ((v.u >> 16) & 1u);
  return (unsigned short)(r >> 16);
}
__device__ inline float bf2f(unsigned short b) {
  union { unsigned int u; float f; } v; v.u = ((unsigned int)b) << 16;
  return v.f;
}

// async global->LDS, 16B per lane. LDS dest = wave-uniform base + lane*16.
__device__ __forceinline__ void gload16(const unsigned short* g, unsigned short* l) {
  __builtin_amdgcn_global_load_lds(
      (const __attribute__((address_space(1))) unsigned int*)g,
      (__attribute__((address_space(3))) unsigned int*)l, 16, 0, 0);
}

// ---------------------------------------------------------------------------
// Merged prep: x cvt (blocks 0..4095), w_qkv transpose+cvt (4096..7167),
// w_out transpose+cvt (7168..8191).
// ---------------------------------------------------------------------------
__device__ void tc_body(const float* __restrict__ w, unsigned short* __restrict__ wT,
                        int K, int N, int bx, int by, int tid,
                        unsigned short (*t)[72]) {
  const int c0 = bx * 64;  // N
  const int r0 = by * 64;  // K
  const int r = tid >> 2;
  const int cb = (tid & 3) * 16;
#pragma unroll
  for (int it = 0; it < 4; ++it) {
    float4 v = *reinterpret_cast<const float4*>(&w[(long)(r0 + r) * N + c0 + cb + 4 * it]);
    t[r][cb + 4 * it + 0] = f2bf(v.x);
    t[r][cb + 4 * it + 1] = f2bf(v.y);
    t[r][cb + 4 * it + 2] = f2bf(v.z);
    t[r][cb + 4 * it + 3] = f2bf(v.w);
  }
  __syncthreads();
  unsigned short o[16];
#pragma unroll
  for (int e = 0; e < 16; ++e) o[e] = t[cb + e][r];
  unsigned short* dst = &wT[(long)(c0 + r) * K + r0 + cb];
  *reinterpret_cast<short8*>(dst) = *reinterpret_cast<short8*>(&o[0]);
  *reinterpret_cast<short8*>(dst + 8) = *reinterpret_cast<short8*>(&o[8]);
}

__global__ __launch_bounds__(256) void prep_all(
    const float* __restrict__ x, const float* __restrict__ w_qkv,
    const float* __restrict__ w_out, unsigned short* __restrict__ x16,
    unsigned short* __restrict__ wqkvT, unsigned short* __restrict__ woutT) {
  __shared__ unsigned short t[64][72];
  const int bid = blockIdx.x;
  const int tid = threadIdx.x;
  if (bid < 4096) {
    const int id = bid * 256 + tid;
    const float4* p = reinterpret_cast<const float4*>(x) + 2 * (size_t)id;
    float4 a = p[0], b = p[1];
    short8 o;
    o[0] = (short)f2bf(a.x); o[1] = (short)f2bf(a.y);
    o[2] = (short)f2bf(a.z); o[3] = (short)f2bf(a.w);
    o[4] = (short)f2bf(b.x); o[5] = (short)f2bf(b.y);
    o[6] = (short)f2bf(b.z); o[7] = (short)f2bf(b.w);
    *reinterpret_cast<short8*>(x16 + 8 * (size_t)id) = o;
  } else if (bid < 7168) {
    const int lb = bid - 4096;
    tc_body(w_qkv, wqkvT, Dn, QKVC, lb % 96, lb / 96, tid, t);
  } else {
    const int lb = bid - 7168;
    tc_body(w_out, woutT, Dn, Dn, lb % 32, lb / 32, tid, t);
  }
}

// ---------------------------------------------------------------------------
// 128x128-tile GEMM main loop, 256 thr = 4 waves (2M x 2N), 64x64/wave,
// BK=64, LDS 64 KiB dbuf -> 2 blocks/CU. m97 2-barrier structure.
// Tile mapping: XCD spread + group-of-8-n inner ordering (8 blocks share an
// A tile back-to-back; 8 B panels = 4 MB stay L2-resident per group).
// ---------------------------------------------------------------------------
#define ABUF(buf) ((buf) * 8192)              // shorts
#define BBUF(buf) (16384 + (buf) * 8192)      // shorts

#define TILE_MAP()                                                             \
  const int nwg = gridDim.x * gridDim.y;                                       \
  const int bid = blockIdx.y * gridDim.x + blockIdx.x;                         \
  const int swz = (bid & 7) * (nwg >> 3) + (bid >> 3);                         \
  const int t_ = swz & 255, grp_ = swz >> 8;                                   \
  const int m0 = (t_ >> 3) * 128;                                              \
  const int n0 = ((t_ & 7) + grp_ * 8) * 128;

#define GEMM128_LOOP(A_, BT_, K_)                                              \
  STAGE(A_ + (long)m0 * K_, ABUF(0));                                          \
  STAGE(BT_ + (long)n0 * K_, BBUF(0));                                         \
  __syncthreads();                                                             \
  for (int t = 0; t < nt; ++t) {                                               \
    const int cb = t & 1;                                                      \
    if (t + 1 < nt) {                                                          \
      const long To = (long)(t + 1) * 64;                                      \
      STAGE(A_ + (long)m0 * K_ + To, ABUF(cb ^ 1));                            \
      STAGE(BT_ + (long)n0 * K_ + To, BBUF(cb ^ 1));                           \
    }                                                                          \
    short8 afr[4][2], bfr[4][2];                                               \
    _Pragma("unroll") for (int mi = 0; mi < 4; ++mi)                           \
      _Pragma("unroll") for (int ks = 0; ks < 2; ++ks)                         \
        afr[mi][ks] = *(const short8*)(lds + ABUF(cb) +                        \
            (wr * 64 + mi * 16 + c) * 64 + (((ks * 4 + g) ^ cg7) << 3));       \
    _Pragma("unroll") for (int ni = 0; ni < 4; ++ni)                           \
      _Pragma("unroll") for (int ks = 0; ks < 2; ++ks)                         \
        bfr[ni][ks] = *(const short8*)(lds + BBUF(cb) +                        \
            (wc * 64 + ni * 16 + c) * 64 + (((ks * 4 + g) ^ cg7) << 3));       \
    __builtin_amdgcn_s_setprio(1);                                             \
    _Pragma("unroll") for (int mi = 0; mi < 4; ++mi)                           \
      _Pragma("unroll") for (int ni = 0; ni < 4; ++ni)                         \
        _Pragma("unroll") for (int ks = 0; ks < 2; ++ks)                       \
          acc[mi][ni] = __builtin_amdgcn_mfma_f32_16x16x32_bf16(               \
              afr[mi][ks], bfr[ni][ks], acc[mi][ni], 0, 0, 0);                 \
    __builtin_amdgcn_s_setprio(0);                                             \
    __syncthreads();                                                           \
  }

// ---------------------------------------------------------------------------
// QKV GEMM with fused rope + head-split + V-transpose epilogue.
// ---------------------------------------------------------------------------
__global__ __launch_bounds__(256, 2) void gemm_qkv(
    const unsigned short* __restrict__ A, const unsigned short* __restrict__ BT,
    const float* __restrict__ rope, const int* __restrict__ tpos,
    unsigned short* __restrict__ qR, unsigned short* __restrict__ kR,
    unsigned short* __restrict__ vT, int K) {
  __shared__ unsigned short lds[32768];  // 64 KiB
  const int tid = threadIdx.x;
  const int wid = tid >> 6, lane = tid & 63;
  const int c = lane & 15, g = lane >> 4;
  const int wr = wid >> 1, wc = wid & 1;
  const int cg7 = c & 7;

  TILE_MAP()

  const int nt = K >> 6;

  float4v acc[4][4];
#pragma unroll
  for (int i = 0; i < 4; ++i)
#pragma unroll
    for (int j = 0; j < 4; ++j) acc[i][j] = (float4v){0.f, 0.f, 0.f, 0.f};

  auto STAGE = [&](const unsigned short* gbase, int sbase) {
#pragma unroll
    for (int j = 0; j < 4; ++j) {
      const int ch = j * 256 + tid;     // 0..1023
      const int r = ch >> 3;            // 0..127
      const int wo = (ch & 7) ^ (r & 7);
      gload16(gbase + (long)r * K + wo * 8, lds + sbase + j * 2048 + wid * 512);
    }
  };

  GEMM128_LOOP(A, BT, K)

  // ---- fused epilogue ----
  const int type = n0 >> 11;            // 0=q 1=k 2=v
  const int h = (n0 & 2047) >> 7;
  const long bh = (long)((m0 >> 10) * Hn + h);
  const int s0 = m0 & 1023;

  if (type == 2) {
#pragma unroll
    for (int mi = 0; mi < 4; ++mi)
#pragma unroll
      for (int ni = 0; ni < 4; ++ni)
#pragma unroll
        for (int j = 0; j < 4; ++j) {
          const int mm = wr * 64 + mi * 16 + g * 4 + j;   // s-local
          const int nn = wc * 64 + ni * 16 + c;           // d
          lds[nn * 136 + mm] = f2bf(acc[mi][ni][j]);
        }
    __syncthreads();
    unsigned short* dst = vT + bh * (long)DHn * Sn + s0;
#pragma unroll
    for (int it = 0; it < 8; ++it) {
      const int cid = it * 256 + tid;
      const int d = cid >> 4;
      const int sl = (cid & 15) * 8;
      short8 v = *reinterpret_cast<const short8*>(lds + d * 136 + sl);
      *reinterpret_cast<short8*>(dst + (long)d * Sn + sl) = v;
    }
  } else {
#pragma unroll
    for (int mi = 0; mi < 4; ++mi)
#pragma unroll
      for (int ni = 0; ni < 4; ++ni)
#pragma unroll
        for (int j = 0; j < 4; ++j) {
          const int mm = wr * 64 + mi * 16 + g * 4 + j;
          const int nn = wc * 64 + ni * 16 + c;
          lds[mm * 136 + nn] = f2bf(acc[mi][ni][j]);
        }
    __syncthreads();
    unsigned short* dst = (type == 0 ? qR : kR) + (bh * Sn + s0) * DHn;
    const float qsc = (type == 0) ? 0.1275174213f : 1.0f;  // log2(e)/sqrt(128)
#pragma unroll
    for (int it = 0; it < 8; ++it) {
      const int cid = it * 256 + tid;
      const int r = cid >> 4;
      const int colc = (cid & 15) * 8;
      union { short8 v; unsigned short u[8]; } iw, ow;
      iw.v = *reinterpret_cast<const short8*>(lds + r * 136 + colc);
      const int pos = tpos[s0 + r];
      const float4* pe = reinterpret_cast<const float4*>(rope) +
                         (long)pos * 64 + (colc >> 1);
#pragma unroll
      for (int p = 0; p < 4; ++p) {
        const float4 m2 = pe[p];
        const float xx = bf2f(iw.u[2 * p]), yy = bf2f(iw.u[2 * p + 1]);
        ow.u[2 * p]     = f2bf((m2.x * xx + m2.y * yy) * qsc);
        ow.u[2 * p + 1] = f2bf((m2.z * xx + m2.w * yy) * qsc);
      }
      *reinterpret_cast<short8*>(dst + (long)r * DHn + colc) = ow.v;
    }
  }
}

// ---------------------------------------------------------------------------
// Out-proj GEMM (f32 out), same 128x128 main loop.
// ---------------------------------------------------------------------------
__global__ __launch_bounds__(256, 2) void gemm_out(
    const unsigned short* __restrict__ A, const unsigned short* __restrict__ BT,
    float* __restrict__ Cout, int N, int K) {
  __shared__ unsigned short lds[32768];
  const int tid = threadIdx.x;
  const int wid = tid >> 6, lane = tid & 63;
  const int c = lane & 15, g = lane >> 4;
  const int wr = wid >> 1, wc = wid & 1;
  const int cg7 = c & 7;

  TILE_MAP()

  const int nt = K >> 6;

  float4v acc[4][4];
#pragma unroll
  for (int i = 0; i < 4; ++i)
#pragma unroll
    for (int j = 0; j < 4; ++j) acc[i][j] = (float4v){0.f, 0.f, 0.f, 0.f};

  auto STAGE = [&](const unsigned short* gbase, int sbase) {
#pragma unroll
    for (int j = 0; j < 4; ++j) {
      const int ch = j * 256 + tid;
      const int r = ch >> 3;
      const int wo = (ch & 7) ^ (r & 7);
      gload16(gbase + (long)r * K + wo * 8, lds + sbase + j * 2048 + wid * 512);
    }
  };

  GEMM128_LOOP(A, BT, K)

#pragma unroll
  for (int mi = 0; mi < 4; ++mi)
#pragma unroll
    for (int ni = 0; ni < 4; ++ni)
#pragma unroll
      for (int j = 0; j < 4; ++j) {
        const int m = m0 + wr * 64 + mi * 16 + g * 4 + j;
        const int n = n0 + wc * 64 + ni * 16 + c;
        Cout[(long)m * N + n] = acc[mi][ni][j];
      }
}
#undef GEMM128_LOOP
#undef TILE_MAP

// ---------------------------------------------------------------------------
// Flash attention v4: 4 waves, KVBLK=64 dbuf, QBLK=128 via two q-subtiles;
// CU-balanced heavy+light pairing (blocks n and n+256 complementary).
// ---------------------------------------------------------------------------
__global__ __launch_bounds__(256, 2) void attn_mfma(
    const unsigned short* __restrict__ qR, const unsigned short* __restrict__ kR,
    const unsigned short* __restrict__ vTd, unsigned short* __restrict__ ctx) {
  __shared__ unsigned short lds[32768];   // K dbuf @0/8192, V dbuf @16384/24576
  __shared__ unsigned short Ps[4][16][72];
  const int n = blockIdx.x;
  const int qp = (n < 256) ? (7 - (n >> 6)) : ((n - 256) >> 6);
  const int hb = n & 63;
  const int h = hb >> 2, b = hb & 3;
  const int tid = threadIdx.x, wid = tid >> 6, lane = tid & 63;
  const int c = lane & 15, g = lane >> 4, cg7 = c & 7;
  const long bh = (long)(b * Hn + h);
  const unsigned short* kbase = kR + bh * Sn * DHn;
  const unsigned short* vbase = vTd + bh * DHn * Sn;

  short8 qf[2][4];
#pragma unroll
  for (int sub = 0; sub < 2; ++sub) {
    const unsigned short* qrow =
        qR + (bh * Sn + qp * 128 + sub * 64 + wid * 16 + c) * DHn;
#pragma unroll
    for (int kc = 0; kc < 4; ++kc)
      qf[sub][kc] = *reinterpret_cast<const short8*>(qrow + kc * 32 + g * 8);
  }

  auto STAGE = [&](int kt, int buf) {
#pragma unroll
    for (int j = 0; j < 4; ++j) {  // K tile [64][128]
      const int ch = j * 256 + tid;
      const int r = ch >> 4, wd = ch & 15;
      const int ws = (wd & 8) | ((wd & 7) ^ (r & 7));
      gload16(kbase + (long)kt * 8192 + r * 128 + ws * 8,
              lds + buf * 8192 + j * 2048 + wid * 512);
    }
#pragma unroll
    for (int j = 0; j < 4; ++j) {  // V^T tile [128][64]
      const int ch = j * 256 + tid;
      const int d = ch >> 3, sw = ch & 7;
      gload16(vbase + (long)d * Sn + kt * 64 + ((sw ^ (d & 7)) << 3),
              lds + 16384 + buf * 8192 + j * 2048 + wid * 512);
    }
  };

  float m[2] = {-INFINITY, -INFINITY}, lsum[2] = {0.f, 0.f};
  float4v otA[8], otB[8];
#pragma unroll
  for (int fd = 0; fd < 8; ++fd) {
    otA[fd] = (float4v){0.f, 0.f, 0.f, 0.f};
    otB[fd] = (float4v){0.f, 0.f, 0.f, 0.f};
  }

  const int ntt = 2 * qp + 2;
  STAGE(0, 0);
  __syncthreads();
  int cur = 0;

  for (int kt = 0; kt < ntt; ++kt) {
    if (kt + 1 < ntt) STAGE(kt + 1, cur ^ 1);

#pragma unroll
    for (int sub = 0; sub < 2; ++sub) {
      if (sub == 0 && kt == ntt - 1) continue;
      float4v* ot = (sub == 0) ? otA : otB;

      float4v scv[4];
#pragma unroll
      for (int f = 0; f < 4; ++f) scv[f] = (float4v){0.f, 0.f, 0.f, 0.f};
      __builtin_amdgcn_s_setprio(1);
#pragma unroll
      for (int f = 0; f < 4; ++f)
#pragma unroll
        for (int kc = 0; kc < 4; ++kc) {
          const int wp = kc * 4 + g;
          const int ws = (wp & 8) | ((wp & 7) ^ cg7);
          short8 kf = *reinterpret_cast<const short8*>(
              lds + cur * 8192 + (f * 16 + c) * 128 + ws * 8);
          scv[f] = __builtin_amdgcn_mfma_f32_16x16x32_bf16(kf, qf[sub][kc],
                                                           scv[f], 0, 0, 0);
        }
      __builtin_amdgcn_s_setprio(0);

      if (kt == 2 * qp + sub) {
        const int qloc = wid * 16 + c;
#pragma unroll
        for (int f = 0; f < 4; ++f)
#pragma unroll
          for (int j = 0; j < 4; ++j)
            if (f * 16 + g * 4 + j > qloc) scv[f][j] = -INFINITY;
      }

      float tmax = -INFINITY;
#pragma unroll
      for (int f = 0; f < 4; ++f)
#pragma unroll
        for (int j = 0; j < 4; ++j) tmax = fmaxf(tmax, scv[f][j]);
      tmax = fmaxf(tmax, __shfl_xor(tmax, 16));
      tmax = fmaxf(tmax, __shfl_xor(tmax, 32));

      float mnew, corr;
      if (__all(tmax <= m[sub] + 8.f)) {  // defer-max
        mnew = m[sub]; corr = 1.f;
      } else {
        mnew = fmaxf(m[sub], tmax);
        corr = exp2f(m[sub] - mnew);
#pragma unroll
        for (int fd = 0; fd < 8; ++fd) ot[fd] *= corr;
      }
      float psum = 0.f;
#pragma unroll
      for (int f = 0; f < 4; ++f)
#pragma unroll
        for (int j = 0; j < 4; ++j) {
          scv[f][j] = exp2f(scv[f][j] - mnew);
          psum += scv[f][j];
        }
      psum += __shfl_xor(psum, 16);
      psum += __shfl_xor(psum, 32);
      lsum[sub] = lsum[sub] * corr + psum;
      m[sub] = mnew;

#pragma unroll
      for (int f = 0; f < 4; ++f) {
        unsigned int lo = (unsigned)f2bf(scv[f][0]) | ((unsigned)f2bf(scv[f][1]) << 16);
        unsigned int hi = (unsigned)f2bf(scv[f][2]) | ((unsigned)f2bf(scv[f][3]) << 16);
        uint2 pk; pk.x = lo; pk.y = hi;
        *reinterpret_cast<uint2*>(&Ps[wid][c][f * 16 + g * 4]) = pk;
      }

      short8 pf0 = *reinterpret_cast<const short8*>(&Ps[wid][c][g * 8]);
      short8 pf1 = *reinterpret_cast<const short8*>(&Ps[wid][c][32 + g * 8]);
      __builtin_amdgcn_s_setprio(1);
#pragma unroll
      for (int fd = 0; fd < 8; ++fd) {
        short8 vf0 = *reinterpret_cast<const short8*>(
            lds + 16384 + cur * 8192 + (fd * 16 + c) * 64 + ((g ^ cg7) << 3));
        short8 vf1 = *reinterpret_cast<const short8*>(
            lds + 16384 + cur * 8192 + (fd * 16 + c) * 64 + (((g + 4) ^ cg7) << 3));
        ot[fd] = __builtin_amdgcn_mfma_f32_16x16x32_bf16(vf0, pf0, ot[fd], 0, 0, 0);
        ot[fd] = __builtin_amdgcn_mfma_f32_16x16x32_bf16(vf1, pf1, ot[fd], 0, 0, 0);
      }
      __builtin_amdgcn_s_setprio(0);
    }

    __syncthreads();
    cur ^= 1;
  }

#pragma unroll
  for (int sub = 0; sub < 2; ++sub) {
    const float4v* ot = (sub == 0) ? otA : otB;
    const float inv = 1.0f / lsum[sub];
    unsigned short* orow =
        ctx + (long)(b * Sn + qp * 128 + sub * 64 + wid * 16 + c) * Dn + h * DHn;
#pragma unroll
    for (int fd = 0; fd < 8; ++fd) {
      const int d = fd * 16 + g * 4;
      uint2 pk;
      pk.x = (unsigned)f2bf(ot[fd][0] * inv) | ((unsigned)f2bf(ot[fd][1] * inv) << 16);
      pk.y = (unsigned)f2bf(ot[fd][2] * inv) | ((unsigned)f2bf(ot[fd][3] * inv) << 16);
      *reinterpret_cast<uint2*>(orow + d) = pk;
    }
  }
}

// ---------------------------------------------------------------------------
extern "C" void kernel_launch(void* const* d_in, const int* in_sizes, int n_in,
                              void* d_out, int out_size, void* d_ws, size_t ws_size,
                              hipStream_t stream) {
  const float* x     = (const float*)d_in[0];
  const float* w_qkv = (const float*)d_in[1];
  const float* w_out = (const float*)d_in[2];
  const float* rope  = (const float*)d_in[3];
  const int*   tpos  = (const int*)d_in[4];
  float* out = (float*)d_out;

  unsigned short* x16    = (unsigned short*)d_ws;
  unsigned short* wqkvT  = x16 + (size_t)BS * Dn;
  unsigned short* woutT  = wqkvT + (size_t)Dn * QKVC;
  unsigned short* qR     = woutT + (size_t)Dn * Dn;
  unsigned short* kR     = qR + (size_t)BS * Dn;
  unsigned short* vT16   = kR + (size_t)BS * Dn;
  unsigned short* ctx16  = vT16 + (size_t)BS * Dn;

  prep_all<<<8192, 256, 0, stream>>>(x, w_qkv, w_out, x16, wqkvT, woutT);
  {
    dim3 grid(BS / 128, QKVC / 128);  // 32 x 48 = 1536 = 3.0 rounds @ 2/CU
    gemm_qkv<<<grid, 256, 0, stream>>>(x16, wqkvT, rope, tpos, qR, kR, vT16, Dn);
  }
  attn_mfma<<<512, 256, 0, stream>>>(qR, kR, vT16, ctx16);
  {
    dim3 grid(BS / 128, Dn / 128);    // 32 x 16 = 512 = 1.0 round @ 2/CU
    gemm_out<<<grid, 256, 0, stream>>>(ctx16, woutT, out, Dn, Dn);
  }
}

// Round 20
// 208.332 us; speedup vs baseline: 1.7971x; 1.0065x over previous
//
#include <hip/hip_runtime.h>
#include <hip/hip_bf16.h>
#include <math.h>

#define Bn 4
#define Sn 1024
#define Dn 2048
#define Hn 16
#define DHn 128
#define BS (Bn * Sn)       // 4096
#define QKVC (3 * Dn)      // 6144

typedef __attribute__((ext_vector_type(8))) short short8;   // 8 x bf16
typedef __attribute__((ext_vector_type(4))) float float4v;  // MFMA acc

// f32 -> bf16 via hardware convert (RNE; compiler pairs into v_cvt_pk_bf16_f32)
__device__ inline unsigned short f2bf(float x) {
  return __builtin_bit_cast(unsigned short, __float2bfloat16(x));
}
__device__ inline float bf2f(unsigned short b) {
  union { unsigned int u; float f; } v; v.u = ((unsigned int)b) << 16;
  return v.f;
}

// async global->LDS, 16B per lane. LDS dest = wave-uniform base + lane*16.
__device__ __forceinline__ void gload16(const unsigned short* g, unsigned short* l) {
  __builtin_amdgcn_global_load_lds(
      (const __attribute__((address_space(1))) unsigned int*)g,
      (__attribute__((address_space(3))) unsigned int*)l, 16, 0, 0);
}

// ---------------------------------------------------------------------------
// Merged prep: x cvt (blocks 0..4095), w_qkv transpose+cvt (4096..7167),
// w_out transpose+cvt (7168..8191).
// ---------------------------------------------------------------------------
__device__ void tc_body(const float* __restrict__ w, unsigned short* __restrict__ wT,
                        int K, int N, int bx, int by, int tid,
                        unsigned short (*t)[72]) {
  const int c0 = bx * 64;  // N
  const int r0 = by * 64;  // K
  const int r = tid >> 2;
  const int cb = (tid & 3) * 16;
#pragma unroll
  for (int it = 0; it < 4; ++it) {
    float4 v = *reinterpret_cast<const float4*>(&w[(long)(r0 + r) * N + c0 + cb + 4 * it]);
    t[r][cb + 4 * it + 0] = f2bf(v.x);
    t[r][cb + 4 * it + 1] = f2bf(v.y);
    t[r][cb + 4 * it + 2] = f2bf(v.z);
    t[r][cb + 4 * it + 3] = f2bf(v.w);
  }
  __syncthreads();
  unsigned short o[16];
#pragma unroll
  for (int e = 0; e < 16; ++e) o[e] = t[cb + e][r];
  unsigned short* dst = &wT[(long)(c0 + r) * K + r0 + cb];
  *reinterpret_cast<short8*>(dst) = *reinterpret_cast<short8*>(&o[0]);
  *reinterpret_cast<short8*>(dst + 8) = *reinterpret_cast<short8*>(&o[8]);
}

__global__ __launch_bounds__(256) void prep_all(
    const float* __restrict__ x, const float* __restrict__ w_qkv,
    const float* __restrict__ w_out, unsigned short* __restrict__ x16,
    unsigned short* __restrict__ wqkvT, unsigned short* __restrict__ woutT) {
  __shared__ unsigned short t[64][72];
  const int bid = blockIdx.x;
  const int tid = threadIdx.x;
  if (bid < 4096) {
    const int id = bid * 256 + tid;
    const float4* p = reinterpret_cast<const float4*>(x) + 2 * (size_t)id;
    float4 a = p[0], b = p[1];
    short8 o;
    o[0] = (short)f2bf(a.x); o[1] = (short)f2bf(a.y);
    o[2] = (short)f2bf(a.z); o[3] = (short)f2bf(a.w);
    o[4] = (short)f2bf(b.x); o[5] = (short)f2bf(b.y);
    o[6] = (short)f2bf(b.z); o[7] = (short)f2bf(b.w);
    *reinterpret_cast<short8*>(x16 + 8 * (size_t)id) = o;
  } else if (bid < 7168) {
    const int lb = bid - 4096;
    tc_body(w_qkv, wqkvT, Dn, QKVC, lb % 96, lb / 96, tid, t);
  } else {
    const int lb = bid - 7168;
    tc_body(w_out, woutT, Dn, Dn, lb % 32, lb / 32, tid, t);
  }
}

// ---------------------------------------------------------------------------
// 128x128-tile GEMM main loop, 256 thr = 4 waves (2M x 2N), 64x64/wave,
// BK=64, LDS 64 KiB dbuf -> 2 blocks/CU. m97 2-barrier structure.
// Tile mapping: XCD spread + group-of-8-n inner ordering.
// ---------------------------------------------------------------------------
#define ABUF(buf) ((buf) * 8192)              // shorts
#define BBUF(buf) (16384 + (buf) * 8192)      // shorts

#define TILE_MAP()                                                             \
  const int nwg = gridDim.x * gridDim.y;                                       \
  const int bid = blockIdx.y * gridDim.x + blockIdx.x;                         \
  const int swz = (bid & 7) * (nwg >> 3) + (bid >> 3);                         \
  const int t_ = swz & 255, grp_ = swz >> 8;                                   \
  const int m0 = (t_ >> 3) * 128;                                              \
  const int n0 = ((t_ & 7) + grp_ * 8) * 128;

#define GEMM128_LOOP(A_, BT_, K_)                                              \
  STAGE(A_ + (long)m0 * K_, ABUF(0));                                          \
  STAGE(BT_ + (long)n0 * K_, BBUF(0));                                         \
  __syncthreads();                                                             \
  for (int t = 0; t < nt; ++t) {                                               \
    const int cb = t & 1;                                                      \
    if (t + 1 < nt) {                                                          \
      const long To = (long)(t + 1) * 64;                                      \
      STAGE(A_ + (long)m0 * K_ + To, ABUF(cb ^ 1));                            \
      STAGE(BT_ + (long)n0 * K_ + To, BBUF(cb ^ 1));                           \
    }                                                                          \
    short8 afr[4][2], bfr[4][2];                                               \
    _Pragma("unroll") for (int mi = 0; mi < 4; ++mi)                           \
      _Pragma("unroll") for (int ks = 0; ks < 2; ++ks)                         \
        afr[mi][ks] = *(const short8*)(lds + ABUF(cb) +                        \
            (wr * 64 + mi * 16 + c) * 64 + (((ks * 4 + g) ^ cg7) << 3));       \
    _Pragma("unroll") for (int ni = 0; ni < 4; ++ni)                           \
      _Pragma("unroll") for (int ks = 0; ks < 2; ++ks)                         \
        bfr[ni][ks] = *(const short8*)(lds + BBUF(cb) +                        \
            (wc * 64 + ni * 16 + c) * 64 + (((ks * 4 + g) ^ cg7) << 3));       \
    __builtin_amdgcn_s_setprio(1);                                             \
    _Pragma("unroll") for (int mi = 0; mi < 4; ++mi)                           \
      _Pragma("unroll") for (int ni = 0; ni < 4; ++ni)                         \
        _Pragma("unroll") for (int ks = 0; ks < 2; ++ks)                       \
          acc[mi][ni] = __builtin_amdgcn_mfma_f32_16x16x32_bf16(               \
              afr[mi][ks], bfr[ni][ks], acc[mi][ni], 0, 0, 0);                 \
    __builtin_amdgcn_s_setprio(0);                                             \
    __syncthreads();                                                           \
  }

// ---------------------------------------------------------------------------
// QKV GEMM with fused rope + head-split + V-transpose epilogue.
// ---------------------------------------------------------------------------
__global__ __launch_bounds__(256, 2) void gemm_qkv(
    const unsigned short* __restrict__ A, const unsigned short* __restrict__ BT,
    const float* __restrict__ rope, const int* __restrict__ tpos,
    unsigned short* __restrict__ qR, unsigned short* __restrict__ kR,
    unsigned short* __restrict__ vT, int K) {
  __shared__ unsigned short lds[32768];  // 64 KiB
  const int tid = threadIdx.x;
  const int wid = tid >> 6, lane = tid & 63;
  const int c = lane & 15, g = lane >> 4;
  const int wr = wid >> 1, wc = wid & 1;
  const int cg7 = c & 7;

  TILE_MAP()

  const int nt = K >> 6;

  float4v acc[4][4];
#pragma unroll
  for (int i = 0; i < 4; ++i)
#pragma unroll
    for (int j = 0; j < 4; ++j) acc[i][j] = (float4v){0.f, 0.f, 0.f, 0.f};

  auto STAGE = [&](const unsigned short* gbase, int sbase) {
#pragma unroll
    for (int j = 0; j < 4; ++j) {
      const int ch = j * 256 + tid;     // 0..1023
      const int r = ch >> 3;            // 0..127
      const int wo = (ch & 7) ^ (r & 7);
      gload16(gbase + (long)r * K + wo * 8, lds + sbase + j * 2048 + wid * 512);
    }
  };

  GEMM128_LOOP(A, BT, K)

  // ---- fused epilogue ----
  const int type = n0 >> 11;            // 0=q 1=k 2=v
  const int h = (n0 & 2047) >> 7;
  const long bh = (long)((m0 >> 10) * Hn + h);
  const int s0 = m0 & 1023;

  if (type == 2) {
#pragma unroll
    for (int mi = 0; mi < 4; ++mi)
#pragma unroll
      for (int ni = 0; ni < 4; ++ni)
#pragma unroll
        for (int j = 0; j < 4; ++j) {
          const int mm = wr * 64 + mi * 16 + g * 4 + j;   // s-local
          const int nn = wc * 64 + ni * 16 + c;           // d
          lds[nn * 136 + mm] = f2bf(acc[mi][ni][j]);
        }
    __syncthreads();
    unsigned short* dst = vT + bh * (long)DHn * Sn + s0;
#pragma unroll
    for (int it = 0; it < 8; ++it) {
      const int cid = it * 256 + tid;
      const int d = cid >> 4;
      const int sl = (cid & 15) * 8;
      short8 v = *reinterpret_cast<const short8*>(lds + d * 136 + sl);
      *reinterpret_cast<short8*>(dst + (long)d * Sn + sl) = v;
    }
  } else {
#pragma unroll
    for (int mi = 0; mi < 4; ++mi)
#pragma unroll
      for (int ni = 0; ni < 4; ++ni)
#pragma unroll
        for (int j = 0; j < 4; ++j) {
          const int mm = wr * 64 + mi * 16 + g * 4 + j;
          const int nn = wc * 64 + ni * 16 + c;
          lds[mm * 136 + nn] = f2bf(acc[mi][ni][j]);
        }
    __syncthreads();
    unsigned short* dst = (type == 0 ? qR : kR) + (bh * Sn + s0) * DHn;
    const float qsc = (type == 0) ? 0.1275174213f : 1.0f;  // log2(e)/sqrt(128)
#pragma unroll
    for (int it = 0; it < 8; ++it) {
      const int cid = it * 256 + tid;
      const int r = cid >> 4;
      const int colc = (cid & 15) * 8;
      union { short8 v; unsigned short u[8]; } iw, ow;
      iw.v = *reinterpret_cast<const short8*>(lds + r * 136 + colc);
      const int pos = tpos[s0 + r];
      const float4* pe = reinterpret_cast<const float4*>(rope) +
                         (long)pos * 64 + (colc >> 1);
#pragma unroll
      for (int p = 0; p < 4; ++p) {
        const float4 m2 = pe[p];
        const float xx = bf2f(iw.u[2 * p]), yy = bf2f(iw.u[2 * p + 1]);
        ow.u[2 * p]     = f2bf((m2.x * xx + m2.y * yy) * qsc);
        ow.u[2 * p + 1] = f2bf((m2.z * xx + m2.w * yy) * qsc);
      }
      *reinterpret_cast<short8*>(dst + (long)r * DHn + colc) = ow.v;
    }
  }
}

// ---------------------------------------------------------------------------
// Out-proj GEMM (f32 out), same 128x128 main loop.
// ---------------------------------------------------------------------------
__global__ __launch_bounds__(256, 2) void gemm_out(
    const unsigned short* __restrict__ A, const unsigned short* __restrict__ BT,
    float* __restrict__ Cout, int N, int K) {
  __shared__ unsigned short lds[32768];
  const int tid = threadIdx.x;
  const int wid = tid >> 6, lane = tid & 63;
  const int c = lane & 15, g = lane >> 4;
  const int wr = wid >> 1, wc = wid & 1;
  const int cg7 = c & 7;

  TILE_MAP()

  const int nt = K >> 6;

  float4v acc[4][4];
#pragma unroll
  for (int i = 0; i < 4; ++i)
#pragma unroll
    for (int j = 0; j < 4; ++j) acc[i][j] = (float4v){0.f, 0.f, 0.f, 0.f};

  auto STAGE = [&](const unsigned short* gbase, int sbase) {
#pragma unroll
    for (int j = 0; j < 4; ++j) {
      const int ch = j * 256 + tid;
      const int r = ch >> 3;
      const int wo = (ch & 7) ^ (r & 7);
      gload16(gbase + (long)r * K + wo * 8, lds + sbase + j * 2048 + wid * 512);
    }
  };

  GEMM128_LOOP(A, BT, K)

#pragma unroll
  for (int mi = 0; mi < 4; ++mi)
#pragma unroll
    for (int ni = 0; ni < 4; ++ni)
#pragma unroll
      for (int j = 0; j < 4; ++j) {
        const int m = m0 + wr * 64 + mi * 16 + g * 4 + j;
        const int n = n0 + wc * 64 + ni * 16 + c;
        Cout[(long)m * N + n] = acc[mi][ni][j];
      }
}
#undef GEMM128_LOOP
#undef TILE_MAP

// ---------------------------------------------------------------------------
// Flash attention v4: 4 waves, KVBLK=64 dbuf, QBLK=128 via two q-subtiles;
// CU-balanced heavy+light pairing (blocks n and n+256 complementary).
// ---------------------------------------------------------------------------
__global__ __launch_bounds__(256, 2) void attn_mfma(
    const unsigned short* __restrict__ qR, const unsigned short* __restrict__ kR,
    const unsigned short* __restrict__ vTd, unsigned short* __restrict__ ctx) {
  __shared__ unsigned short lds[32768];   // K dbuf @0/8192, V dbuf @16384/24576
  __shared__ unsigned short Ps[4][16][72];
  const int n = blockIdx.x;
  const int qp = (n < 256) ? (7 - (n >> 6)) : ((n - 256) >> 6);
  const int hb = n & 63;
  const int h = hb >> 2, b = hb & 3;
  const int tid = threadIdx.x, wid = tid >> 6, lane = tid & 63;
  const int c = lane & 15, g = lane >> 4, cg7 = c & 7;
  const long bh = (long)(b * Hn + h);
  const unsigned short* kbase = kR + bh * Sn * DHn;
  const unsigned short* vbase = vTd + bh * DHn * Sn;

  short8 qf[2][4];
#pragma unroll
  for (int sub = 0; sub < 2; ++sub) {
    const unsigned short* qrow =
        qR + (bh * Sn + qp * 128 + sub * 64 + wid * 16 + c) * DHn;
#pragma unroll
    for (int kc = 0; kc < 4; ++kc)
      qf[sub][kc] = *reinterpret_cast<const short8*>(qrow + kc * 32 + g * 8);
  }

  auto STAGE = [&](int kt, int buf) {
#pragma unroll
    for (int j = 0; j < 4; ++j) {  // K tile [64][128]
      const int ch = j * 256 + tid;
      const int r = ch >> 4, wd = ch & 15;
      const int ws = (wd & 8) | ((wd & 7) ^ (r & 7));
      gload16(kbase + (long)kt * 8192 + r * 128 + ws * 8,
              lds + buf * 8192 + j * 2048 + wid * 512);
    }
#pragma unroll
    for (int j = 0; j < 4; ++j) {  // V^T tile [128][64]
      const int ch = j * 256 + tid;
      const int d = ch >> 3, sw = ch & 7;
      gload16(vbase + (long)d * Sn + kt * 64 + ((sw ^ (d & 7)) << 3),
              lds + 16384 + buf * 8192 + j * 2048 + wid * 512);
    }
  };

  float m[2] = {-INFINITY, -INFINITY}, lsum[2] = {0.f, 0.f};
  float4v otA[8], otB[8];
#pragma unroll
  for (int fd = 0; fd < 8; ++fd) {
    otA[fd] = (float4v){0.f, 0.f, 0.f, 0.f};
    otB[fd] = (float4v){0.f, 0.f, 0.f, 0.f};
  }

  const int ntt = 2 * qp + 2;
  STAGE(0, 0);
  __syncthreads();
  int cur = 0;

  for (int kt = 0; kt < ntt; ++kt) {
    if (kt + 1 < ntt) STAGE(kt + 1, cur ^ 1);

#pragma unroll
    for (int sub = 0; sub < 2; ++sub) {
      if (sub == 0 && kt == ntt - 1) continue;
      float4v* ot = (sub == 0) ? otA : otB;

      float4v scv[4];
#pragma unroll
      for (int f = 0; f < 4; ++f) scv[f] = (float4v){0.f, 0.f, 0.f, 0.f};
      __builtin_amdgcn_s_setprio(1);
#pragma unroll
      for (int f = 0; f < 4; ++f)
#pragma unroll
        for (int kc = 0; kc < 4; ++kc) {
          const int wp = kc * 4 + g;
          const int ws = (wp & 8) | ((wp & 7) ^ cg7);
          short8 kf = *reinterpret_cast<const short8*>(
              lds + cur * 8192 + (f * 16 + c) * 128 + ws * 8);
          scv[f] = __builtin_amdgcn_mfma_f32_16x16x32_bf16(kf, qf[sub][kc],
                                                           scv[f], 0, 0, 0);
        }
      __builtin_amdgcn_s_setprio(0);

      if (kt == 2 * qp + sub) {
        const int qloc = wid * 16 + c;
#pragma unroll
        for (int f = 0; f < 4; ++f)
#pragma unroll
          for (int j = 0; j < 4; ++j)
            if (f * 16 + g * 4 + j > qloc) scv[f][j] = -INFINITY;
      }

      float tmax = -INFINITY;
#pragma unroll
      for (int f = 0; f < 4; ++f)
#pragma unroll
        for (int j = 0; j < 4; ++j) tmax = fmaxf(tmax, scv[f][j]);
      tmax = fmaxf(tmax, __shfl_xor(tmax, 16));
      tmax = fmaxf(tmax, __shfl_xor(tmax, 32));

      float mnew, corr;
      if (__all(tmax <= m[sub] + 8.f)) {  // defer-max
        mnew = m[sub]; corr = 1.f;
      } else {
        mnew = fmaxf(m[sub], tmax);
        corr = exp2f(m[sub] - mnew);
#pragma unroll
        for (int fd = 0; fd < 8; ++fd) ot[fd] *= corr;
      }
      float psum = 0.f;
#pragma unroll
      for (int f = 0; f < 4; ++f)
#pragma unroll
        for (int j = 0; j < 4; ++j) {
          scv[f][j] = exp2f(scv[f][j] - mnew);
          psum += scv[f][j];
        }
      psum += __shfl_xor(psum, 16);
      psum += __shfl_xor(psum, 32);
      lsum[sub] = lsum[sub] * corr + psum;
      m[sub] = mnew;

#pragma unroll
      for (int f = 0; f < 4; ++f) {
        unsigned int lo = (unsigned)f2bf(scv[f][0]) | ((unsigned)f2bf(scv[f][1]) << 16);
        unsigned int hi = (unsigned)f2bf(scv[f][2]) | ((unsigned)f2bf(scv[f][3]) << 16);
        uint2 pk; pk.x = lo; pk.y = hi;
        *reinterpret_cast<uint2*>(&Ps[wid][c][f * 16 + g * 4]) = pk;
      }

      short8 pf0 = *reinterpret_cast<const short8*>(&Ps[wid][c][g * 8]);
      short8 pf1 = *reinterpret_cast<const short8*>(&Ps[wid][c][32 + g * 8]);
      __builtin_amdgcn_s_setprio(1);
#pragma unroll
      for (int fd = 0; fd < 8; ++fd) {
        short8 vf0 = *reinterpret_cast<const short8*>(
            lds + 16384 + cur * 8192 + (fd * 16 + c) * 64 + ((g ^ cg7) << 3));
        short8 vf1 = *reinterpret_cast<const short8*>(
            lds + 16384 + cur * 8192 + (fd * 16 + c) * 64 + (((g + 4) ^ cg7) << 3));
        ot[fd] = __builtin_amdgcn_mfma_f32_16x16x32_bf16(vf0, pf0, ot[fd], 0, 0, 0);
        ot[fd] = __builtin_amdgcn_mfma_f32_16x16x32_bf16(vf1, pf1, ot[fd], 0, 0, 0);
      }
      __builtin_amdgcn_s_setprio(0);
    }

    __syncthreads();
    cur ^= 1;
  }

#pragma unroll
  for (int sub = 0; sub < 2; ++sub) {
    const float4v* ot = (sub == 0) ? otA : otB;
    const float inv = 1.0f / lsum[sub];
    unsigned short* orow =
        ctx + (long)(b * Sn + qp * 128 + sub * 64 + wid * 16 + c) * Dn + h * DHn;
#pragma unroll
    for (int fd = 0; fd < 8; ++fd) {
      const int d = fd * 16 + g * 4;
      uint2 pk;
      pk.x = (unsigned)f2bf(ot[fd][0] * inv) | ((unsigned)f2bf(ot[fd][1] * inv) << 16);
      pk.y = (unsigned)f2bf(ot[fd][2] * inv) | ((unsigned)f2bf(ot[fd][3] * inv) << 16);
      *reinterpret_cast<uint2*>(orow + d) = pk;
    }
  }
}

// ---------------------------------------------------------------------------
extern "C" void kernel_launch(void* const* d_in, const int* in_sizes, int n_in,
                              void* d_out, int out_size, void* d_ws, size_t ws_size,
                              hipStream_t stream) {
  const float* x     = (const float*)d_in[0];
  const float* w_qkv = (const float*)d_in[1];
  const float* w_out = (const float*)d_in[2];
  const float* rope  = (const float*)d_in[3];
  const int*   tpos  = (const int*)d_in[4];
  float* out = (float*)d_out;

  unsigned short* x16    = (unsigned short*)d_ws;
  unsigned short* wqkvT  = x16 + (size_t)BS * Dn;
  unsigned short* woutT  = wqkvT + (size_t)Dn * QKVC;
  unsigned short* qR     = woutT + (size_t)Dn * Dn;
  unsigned short* kR     = qR + (size_t)BS * Dn;
  unsigned short* vT16   = kR + (size_t)BS * Dn;
  unsigned short* ctx16  = vT16 + (size_t)BS * Dn;

  prep_all<<<8192, 256, 0, stream>>>(x, w_qkv, w_out, x16, wqkvT, woutT);
  {
    dim3 grid(BS / 128, QKVC / 128);  // 32 x 48 = 1536 = 3.0 rounds @ 2/CU
    gemm_qkv<<<grid, 256, 0, stream>>>(x16, wqkvT, rope, tpos, qR, kR, vT16, Dn);
  }
  attn_mfma<<<512, 256, 0, stream>>>(qR, kR, vT16, ctx16);
  {
    dim3 grid(BS / 128, Dn / 128);    // 32 x 16 = 512 = 1.0 round @ 2/CU
    gemm_out<<<grid, 256, 0, stream>>>(ctx16, woutT, out, Dn, Dn);
  }
}